// Round 8
// baseline (308.858 us; speedup 1.0000x reference)
//
#include <hip/hip_runtime.h>
#include <math.h>

#define EPSF 1e-20f
#define Bv 4
#define Cv 32
#define Ov 32
#define Hv 256
#define Wv 256
#define HOv 128
#define WOv 128
#define NPIX (HOv * WOv)          // 16384
#define HALF_OUT (Bv * Ov * NPIX) // 2,097,152

// ext_vector_type aliases: __builtin_nontemporal_* rejects HIP_vector_type
// (float4/float2) pointers but accepts these (R7 compile error).
typedef float f4v __attribute__((ext_vector_type(4)));
typedef float f2v __attribute__((ext_vector_type(2)));

__device__ __forceinline__ float softplus_f(float x) {
    return fmaxf(x, 0.0f) + log1pf(__expf(-fabsf(x)));
}
__device__ __forceinline__ float frcp(float x) {
    return __builtin_amdgcn_rcpf(x);
}

__device__ __forceinline__ float4 gload4(const float* p) {
    float4 r;
    asm volatile("global_load_dwordx4 %0, %1, off" : "=v"(r) : "v"(p));
    return r;
}
__device__ __forceinline__ float2 gload2(const float* p) {
    float2 r;
    asm volatile("global_load_dwordx2 %0, %1, off" : "=v"(r) : "v"(p));
    return r;
}
__device__ __forceinline__ void vm_drain() {
    asm volatile("s_waitcnt vmcnt(0)" ::: "memory");
    __builtin_amdgcn_sched_barrier(0);  // rule #18 fence
}

// ws layout (floats):
//  [0..31]     wp (softplus)
//  [32..319]   sw (c*9+k)
//  [320..1343] cw (o*32+c)
//  [1344] 1/(sum_sw+EPS)   [1345] 1/(sum_cw+EPS)
//  [2048 ...]  float2 buf[(b*32+c)*16384 + pix] = {cgx_sp*gx_sp, cgx_sp} (16.8MB)
#define WS_BUF_OFF 2048
#define WS_NEEDED (WS_BUF_OFF * 4 + (size_t)Bv * Cv * NPIX * 8)

__global__ void prep_kernel(const float* __restrict__ wp_raw,
                            const float* __restrict__ sw_raw,
                            const float* __restrict__ cw_raw,
                            float* __restrict__ ws) {
    __shared__ float red_sw[256];
    __shared__ float red_cw[256];
    const int t = threadIdx.x;
    float acc_sw = 0.f, acc_cw = 0.f;
    if (t < 32) ws[t] = softplus_f(wp_raw[t]);
    for (int i = t; i < 288; i += 256) {
        float v = softplus_f(sw_raw[i]);
        ws[32 + i] = v;
        acc_sw += v;
    }
    for (int i = t; i < 1024; i += 256) {
        float v = softplus_f(cw_raw[i]);
        ws[320 + i] = v;
        acc_cw += v;
    }
    red_sw[t] = acc_sw;
    red_cw[t] = acc_cw;
    __syncthreads();
    for (int st = 128; st > 0; st >>= 1) {
        if (t < st) { red_sw[t] += red_sw[t + st]; red_cw[t] += red_cw[t + st]; }
        __syncthreads();
    }
    if (t == 0) {
        ws[1344] = 1.0f / (red_sw[0] + EPSF);
        ws[1345] = 1.0f / (red_cw[0] + EPSF);
    }
}

// ================= K1 v4: R6 LDS-staged tile + NT sprod ===================
// ROUNDS 0-6: time invariant (~86-94us) across schedule/traffic/occupancy/
// access-structure changes. Shared invariant: 243MB reads/iter with working
// set (248MB) ~ LLC capacity (256MB) -> thrash. THIS ROUND: sprod (75.5MB,
// read exactly once, zero reuse) is loaded NON-TEMPORAL so it stops
// evicting the 5 reusable input arrays (167.7MB). Resident set ~185MB <<
// 256MB -> inputs stay LLC-hot, FETCH should drop to ~sprod+residual.
__global__ __launch_bounds__(256, 2)
void k1_spatial(const float* __restrict__ d,  const float* __restrict__ cd,
                const float* __restrict__ s,  const float* __restrict__ gx,
                const float* __restrict__ cgx, const float* __restrict__ sprod,
                const float* __restrict__ ws, float2* __restrict__ buf) {
    __shared__ float lds[16128];          // [5][9][256] in + [9][256] ga + [9][256] ca
    float* inL = lds;                     // a*2304 + r*256 + w
    float* gaL = lds + 11520;
    float* caL = lds + 13824;

    const int t  = threadIdx.x;
    const int l  = t & 63;
    const int q  = t >> 6;                // wave id = local out-row
    const int z  = blockIdx.x >> 5;       // slice 0..127 (b*32+c)
    const int rt = blockIdx.x & 31;       // row-tile 0..31
    const int c  = z & 31;

    const float wpc = ws[c];
    const float inv_wp1 = frcp(wpc + 1.0f);
    const float inv_sumsw = ws[1344];
    const float* sw_c = ws + 32 + c * 9;

    const int ho0     = rt * 4;
    const int h_top   = 2 * ho0 - 1;
    const bool top    = (rt == 0);
    const int h_start = top ? 0 : h_top;       // first staged global row
    const int nf4     = top ? 512 : 576;       // float4s per array (8 or 9 rows)
    const int dof     = top ? 256 : 0;         // LDS float shift (rows 1..8)
    const int gbase   = z * (Hv * Wv) + h_start * Wv;

    // ---- staging loads: 5 long contiguous streams (regs), all clustered ----
    float4 st[5][3];
#pragma unroll
    for (int a = 0; a < 5; ++a) {
        const float* gp = (a == 0) ? d : (a == 1) ? cd : (a == 2) ? s
                        : (a == 3) ? gx : cgx;
#pragma unroll
        for (int k = 0; k < 3; ++k) {
            const int o = t + k * 256;         // float4 index within array block
            if (o < nf4) st[a][k] = gload4(gp + gbase + 4 * o);
        }
    }
    // sprod for this thread's 2 output pixels: NON-TEMPORAL (once-read data;
    // keep it out of L2/LLC so the reusable arrays stay resident)
    const int ho  = ho0 + q;
    const int sp0 = (z * 9 * HOv + ho) * WOv + 2 * l;
    f2v sp[9];
#pragma unroll
    for (int k = 0; k < 9; ++k)
        sp[k] = __builtin_nontemporal_load(
                    (const f2v*)(sprod + sp0 + k * NPIX));

    vm_drain();   // drain the asm staging cluster

    // ---- LDS fill (ds_write_b128, conflict-free: lanes consecutive) ----
#pragma unroll
    for (int a = 0; a < 5; ++a) {
#pragma unroll
        for (int k = 0; k < 3; ++k) {
            const int o = t + k * 256;
            if (o < nf4)
                *(float4*)(inL + a * 2304 + dof + 4 * o) = st[a][k];
        }
    }
    __syncthreads();

    // ---- stage A: pointwise, one px per (thread, row): r=j, w=t ----
#pragma unroll
    for (int j = 0; j < 9; ++j) {
        const int o = j * 256 + t;
        const float dV  = inL[0 * 2304 + o];
        const float cdV = inL[1 * 2304 + o];
        const float sV  = inL[2 * 2304 + o];
        const float gV  = inL[3 * 2304 + o];
        const float cV  = inL[4 * 2304 + o];
        const bool mL = (t != Wv - 1);         // pad_r zeros last col
        const bool mR = (t != 0);              // pad_l zeros first col
        const float dL  = mL ? dV  : 0.f;
        const float cdL = mL ? cdV : 0.f;
        const float sL  = mL ? sV  : 0.f;
        const float dR  = mR ? dV  : 0.f;
        const float cdR = mR ? cdV : 0.f;
        const float sR  = mR ? sV  : 0.f;
        const float cgx_ds = sV * sL * sR * cdL * cdR;
        const float height = (cdL * dL + cdR * dR) * frcp(cdL + cdR + EPSF);
        const float gx_ds  = (dR - dL) * 0.5f * frcp(height + EPSF);
        const float a_ = wpc * cV;
        const float g_ = (a_ * gV + cgx_ds * gx_ds) * frcp(a_ + cgx_ds + EPSF);
        const float c_ = (a_ + cgx_ds) * inv_wp1;
        const bool vrow = (j > 0) || !top;     // LDS row 0 invalid only for rt==0
        gaL[o] = vrow ? g_ : 0.f;
        caL[o] = vrow ? c_ : 0.f;
    }
    __syncthreads();

    // ---- 9-tap gather from LDS + sprod + sw ----
    float n0 = 0.f, d0 = 0.f, n1 = 0.f, d1 = 0.f;
#pragma unroll
    for (int ki = 0; ki < 3; ++ki) {
        const int ro = (2 * q + ki) * 256;
        const float4 g4 = *(const float4*)(gaL + ro + 4 * l);
        const float4 c4 = *(const float4*)(caL + ro + 4 * l);
        const int eo = ro + (l ? 4 * l - 1 : 0);
        float geL = gaL[eo];
        float ceL = caL[eo];
        geL = l ? geL : 0.f;                   // col -1 tap is zero
        ceL = l ? ceL : 0.f;
        const float sw0 = sw_c[3 * ki + 0];
        const float sw1 = sw_c[3 * ki + 1];
        const float sw2 = sw_c[3 * ki + 2];
        float cp;
        // pixel wo0 = 2l : taps cols 4l-1, 4l, 4l+1
        cp = ceL  * sp[3 * ki + 0].x * sw0; d0 += cp; n0 = fmaf(cp, geL,  n0);
        cp = c4.x * sp[3 * ki + 1].x * sw1; d0 += cp; n0 = fmaf(cp, g4.x, n0);
        cp = c4.y * sp[3 * ki + 2].x * sw2; d0 += cp; n0 = fmaf(cp, g4.y, n0);
        // pixel wo1 = 2l+1 : taps cols 4l+1, 4l+2, 4l+3
        cp = c4.y * sp[3 * ki + 0].y * sw0; d1 += cp; n1 = fmaf(cp, g4.y, n1);
        cp = c4.z * sp[3 * ki + 1].y * sw1; d1 += cp; n1 = fmaf(cp, g4.z, n1);
        cp = c4.w * sp[3 * ki + 2].y * sw2; d1 += cp; n1 = fmaf(cp, g4.w, n1);
    }
    const float gx0 = n0 * frcp(d0 + EPSF);
    const float cg0 = d0 * inv_sumsw;
    const float gx1 = n1 * frcp(d1 + EPSF);
    const float cg1 = d1 * inv_sumsw;
    float4 ov = {cg0 * gx0, cg0, cg1 * gx1, cg1};
    *(float4*)(buf + (size_t)z * NPIX + ho * WOv + 2 * l) = ov;
}

// ================= K2: 32->32 channel mix (o split in 2 groups) ===========
// out is write-once/never-read: NT stores keep it from occupying LLC.
__global__ __launch_bounds__(256, 2)
void k2_channel(const float2* __restrict__ buf, const float* __restrict__ ws,
                const float* __restrict__ bias, float* __restrict__ out) {
    const int pg  = blockIdx.x * 256 + threadIdx.x;  // 0..65535
    const int b   = pg >> 14;
    const int pp  = pg & (NPIX - 1);
    const int grp = blockIdx.y;                      // 0..1
    const float* cw_t = ws + 320;
    const float inv_sumcw = ws[1345];

    const int cbase = b * Cv * NPIX + pp;

    float2 v[Cv];
#pragma unroll
    for (int cc = 0; cc < Cv; ++cc)
        v[cc] = gload2((const float*)(buf + cbase + cc * NPIX));

    vm_drain();

    float nom2[16], den2[16];
#pragma unroll
    for (int i = 0; i < 16; ++i) { nom2[i] = 0.f; den2[i] = 0.f; }

#pragma unroll
    for (int cc = 0; cc < Cv; ++cc) {
#pragma unroll
        for (int oi = 0; oi < 16; ++oi) {
            const float w_ = cw_t[(grp * 16 + oi) * Cv + cc];  // uniform
            nom2[oi] = fmaf(v[cc].x, w_, nom2[oi]);
            den2[oi] = fmaf(v[cc].y, w_, den2[oi]);
        }
    }
#pragma unroll
    for (int oi = 0; oi < 16; ++oi) {
        const int o = grp * 16 + oi;
        const int p = (b * Ov + o) * NPIX + pp;
        const float dn = den2[oi];
        const float g  = nom2[oi] * frcp(dn + EPSF) + bias[o];
        __builtin_nontemporal_store(g * 2.0f, out + p);
        __builtin_nontemporal_store(dn * inv_sumcw * 0.25f, out + HALF_OUT + p);
    }
}

// ================= P_STREAM: diagnostic ceiling probe =====================
// Reads the IDENTICAL 243.3MB k1 reads, but as perfect grid-strided linear
// float4 streams (the m13-copy pattern), all non-temporal so it neither
// pollutes nor depends on LLC residency. Its counter row = the platform's
// real service ceiling for this working set. If ~40us: 6TB/s available and
// k1's gap is closable. If ~85us: ~3TB/s cap -> k1 is at the structural
// ceiling. Writes 8MB of sums into buf (overwritten by next iter's k1).
#define PS_NT (2048 * 256)
__global__ __launch_bounds__(256)
void p_stream(const float* __restrict__ d,  const float* __restrict__ cd,
              const float* __restrict__ s,  const float* __restrict__ gx,
              const float* __restrict__ cgx, const float* __restrict__ sprod,
              float* __restrict__ scratch) {
    const int tid = blockIdx.x * 256 + threadIdx.x;   // 0..524287
    f4v acc = {0.f, 0.f, 0.f, 0.f};
#pragma unroll
    for (int a = 0; a < 5; ++a) {
        const float* gp = (a == 0) ? d : (a == 1) ? cd : (a == 2) ? s
                        : (a == 3) ? gx : cgx;
        const f4v* p4 = (const f4v*)gp;
#pragma unroll
        for (int k = 0; k < 4; ++k) {          // 4 * 524288 = 2,097,152 f4 ✓
            f4v v = __builtin_nontemporal_load(p4 + tid + k * PS_NT);
            acc += v;
        }
    }
    const f4v* sp4 = (const f4v*)sprod;
#pragma unroll
    for (int k = 0; k < 9; ++k) {              // 9 * 524288 = 4,718,592 f4 ✓
        f4v v = __builtin_nontemporal_load(sp4 + tid + k * PS_NT);
        acc += v;
    }
    __builtin_nontemporal_store(acc, (f4v*)scratch + tid);
}

// ================= fallback: fully fused (round-1) kernel =================
#define TH 4
#define TW 32
#define IH 9
#define IW 65
#define IWP 66
#define NTILE (IH * IW)

__global__ __launch_bounds__(128)
void main_kernel(const float* __restrict__ d,  const float* __restrict__ cd,
                 const float* __restrict__ s,  const float* __restrict__ gx,
                 const float* __restrict__ cgx, const float* __restrict__ sprod,
                 const float* __restrict__ bias, const float* __restrict__ ws,
                 float* __restrict__ out) {
    __shared__ float lgx[IH][IWP];
    __shared__ float lcgx[IH][IWP];
    const int t    = threadIdx.x;
    const int wo_l = t & 31;
    const int ho_l = t >> 5;
    const int wo0  = blockIdx.x * TW;
    const int ho0  = blockIdx.y * TH;
    const int b    = blockIdx.z;
    const int ho   = ho0 + ho_l;
    const int wo   = wo0 + wo_l;
    const float* sw_t = ws + 32;
    const float* cw_t = ws + 320;
    const float inv_sumsw = ws[1344];
    const float inv_sumcw = ws[1345];
    float nom2[Ov], den2[Ov];
#pragma unroll
    for (int o = 0; o < Ov; ++o) { nom2[o] = 0.f; den2[o] = 0.f; }
    const int h_base = 2 * ho0 - 1;
    const int w_base = 2 * wo0 - 1;
    for (int c = 0; c < Cv; ++c) {
        const float wpc = ws[c];
        const float inv_wp1 = frcp(wpc + 1.0f);
        const int ibase = (b * Cv + c) * (Hv * Wv);
        for (int idx = t; idx < NTILE; idx += 128) {
            const int r  = idx / IW;
            const int cc = idx - r * IW;
            const int h  = h_base + r;
            const int w  = w_base + cc;
            float gxn = 0.f, cgxn = 0.f;
            if ((unsigned)h < (unsigned)Hv && (unsigned)w < (unsigned)Wv) {
                const int p = ibase + h * Wv + w;
                const float dv = d[p], cdv = cd[p], sv = s[p];
                const float gxv = gx[p], cgxv = cgx[p];
                const bool mLb = (w != Wv - 1);
                const bool mRb = (w != 0);
                const float dL = mLb ? dv : 0.f, cdL = mLb ? cdv : 0.f, sL = mLb ? sv : 0.f;
                const float dR = mRb ? dv : 0.f, cdR = mRb ? cdv : 0.f, sR = mRb ? sv : 0.f;
                const float cgx_ds = sv * sL * sR * cdL * cdR;
                const float height = (cdL * dL + cdR * dR) * frcp(cdL + cdR + EPSF);
                const float gx_ds  = (dR - dL) * 0.5f * frcp(height + EPSF);
                const float a = wpc * cgxv;
                gxn  = (a * gxv + cgx_ds * gx_ds) * frcp(a + cgx_ds + EPSF);
                cgxn = (a + cgx_ds) * inv_wp1;
            }
            lgx[r][cc]  = gxn;
            lcgx[r][cc] = cgxn;
        }
        __syncthreads();
        const int spb = ((b * Cv + c) * 9 * HOv + ho) * WOv + wo;
        float nom = 0.f, den = 0.f;
#pragma unroll
        for (int k = 0; k < 9; ++k) {
            const int ki = k / 3;
            const int kj = k - ki * 3;
            const float gxr  = lgx[2 * ho_l + ki][2 * wo_l + kj];
            const float cgxr = lcgx[2 * ho_l + ki][2 * wo_l + kj];
            const float spv  = sprod[spb + k * NPIX];
            const float cp   = cgxr * spv * sw_t[c * 9 + k];
            den += cp;
            nom = fmaf(cp, gxr, nom);
        }
        const float gx_sp  = nom * frcp(den + EPSF);
        const float cgx_sp = den * inv_sumsw;
        const float t1 = cgx_sp * gx_sp;
#pragma unroll
        for (int o = 0; o < Ov; ++o) {
            const float w_ = cw_t[o * Cv + c];
            nom2[o] = fmaf(t1, w_, nom2[o]);
            den2[o] = fmaf(cgx_sp, w_, den2[o]);
        }
        __syncthreads();
    }
#pragma unroll
    for (int o = 0; o < Ov; ++o) {
        const int p = ((b * Ov + o) * HOv + ho) * WOv + wo;
        const float dn = den2[o];
        const float g  = nom2[o] * frcp(dn + EPSF) + bias[o];
        out[p]            = g * 2.0f;
        out[HALF_OUT + p] = dn * inv_sumcw * 0.25f;
    }
}

extern "C" void kernel_launch(void* const* d_in, const int* in_sizes, int n_in,
                              void* d_out, int out_size, void* d_ws, size_t ws_size,
                              hipStream_t stream) {
    const float* d_ptr    = (const float*)d_in[0];
    const float* cd_ptr   = (const float*)d_in[1];
    const float* s_ptr    = (const float*)d_in[2];
    // d_in[3] = cs : unused by the reference
    const float* gx_ptr   = (const float*)d_in[4];
    const float* cgx_ptr  = (const float*)d_in[5];
    const float* sp_ptr   = (const float*)d_in[6];
    const float* wp_ptr   = (const float*)d_in[7];
    const float* sw_ptr   = (const float*)d_in[8];
    const float* cw_ptr   = (const float*)d_in[9];
    const float* bias_ptr = (const float*)d_in[10];
    float* out = (float*)d_out;
    float* ws  = (float*)d_ws;

    prep_kernel<<<1, 256, 0, stream>>>(wp_ptr, sw_ptr, cw_ptr, ws);

    if (ws_size >= WS_NEEDED) {
        float2* buf = (float2*)(ws + WS_BUF_OFF);
        // 4096 blocks = 128 slices x 32 row-tiles; 4 out rows/block.
        k1_spatial<<<4096, 256, 0, stream>>>(d_ptr, cd_ptr, s_ptr, gx_ptr, cgx_ptr,
                                             sp_ptr, ws, buf);
        dim3 g2((Bv * NPIX) / 256, 2, 1);        // 256 x 2 blocks
        k2_channel<<<g2, 256, 0, stream>>>(buf, ws, bias_ptr, out);
        // Diagnostic ceiling probe (counter row only; remove next round).
        p_stream<<<2048, 256, 0, stream>>>(d_ptr, cd_ptr, s_ptr, gx_ptr, cgx_ptr,
                                           sp_ptr, (float*)buf);
    } else {
        dim3 grid(WOv / TW, HOv / TH, Bv);
        main_kernel<<<grid, 128, 0, stream>>>(d_ptr, cd_ptr, s_ptr, gx_ptr, cgx_ptr,
                                              sp_ptr, bias_ptr, ws, out);
    }
}

// Round 9
// 259.888 us; speedup vs baseline: 1.1884x; 1.1884x over previous
//
#include <hip/hip_runtime.h>
#include <math.h>

#define EPSF 1e-20f
#define Bv 4
#define Cv 32
#define Ov 32
#define Hv 256
#define Wv 256
#define HOv 128
#define WOv 128
#define NPIX (HOv * WOv)          // 16384
#define HALF_OUT (Bv * Ov * NPIX) // 2,097,152

// ext_vector_type aliases: __builtin_nontemporal_* rejects HIP_vector_type
// (float4/float2) pointers but accepts these.
typedef float f4v __attribute__((ext_vector_type(4)));
typedef float f2v __attribute__((ext_vector_type(2)));

__device__ __forceinline__ float softplus_f(float x) {
    return fmaxf(x, 0.0f) + log1pf(__expf(-fabsf(x)));
}
__device__ __forceinline__ float frcp(float x) {
    return __builtin_amdgcn_rcpf(x);
}

__device__ __forceinline__ float2 gload2(const float* p) {
    float2 r;
    asm volatile("global_load_dwordx2 %0, %1, off" : "=v"(r) : "v"(p));
    return r;
}
__device__ __forceinline__ void vm_drain() {
    asm volatile("s_waitcnt vmcnt(0)" ::: "memory");
    __builtin_amdgcn_sched_barrier(0);  // rule #18 fence
}

// ws layout (floats):
//  [0..31]     wp (softplus)
//  [32..319]   sw (c*9+k)
//  [320..1343] cw (o*32+c)
//  [1344] 1/(sum_sw+EPS)   [1345] 1/(sum_cw+EPS)
//  [2048 ...]  float2 buf[(b*32+c)*16384 + pix] = {cgx_sp*gx_sp, cgx_sp} (16.8MB)
#define WS_BUF_OFF 2048
#define WS_NEEDED (WS_BUF_OFF * 4 + (size_t)Bv * Cv * NPIX * 8)

__global__ void prep_kernel(const float* __restrict__ wp_raw,
                            const float* __restrict__ sw_raw,
                            const float* __restrict__ cw_raw,
                            float* __restrict__ ws) {
    __shared__ float red_sw[256];
    __shared__ float red_cw[256];
    const int t = threadIdx.x;
    float acc_sw = 0.f, acc_cw = 0.f;
    if (t < 32) ws[t] = softplus_f(wp_raw[t]);
    for (int i = t; i < 288; i += 256) {
        float v = softplus_f(sw_raw[i]);
        ws[32 + i] = v;
        acc_sw += v;
    }
    for (int i = t; i < 1024; i += 256) {
        float v = softplus_f(cw_raw[i]);
        ws[320 + i] = v;
        acc_cw += v;
    }
    red_sw[t] = acc_sw;
    red_cw[t] = acc_cw;
    __syncthreads();
    for (int st = 128; st > 0; st >>= 1) {
        if (t < st) { red_sw[t] += red_sw[t + st]; red_cw[t] += red_cw[t + st]; }
        __syncthreads();
    }
    if (t == 0) {
        ws[1344] = 1.0f / (red_sw[0] + EPSF);
        ws[1345] = 1.0f / (red_cw[0] + EPSF);
    }
}

// ================= K1 v5: LDS-staged tile, ALL reads non-temporal =========
// R8 EVIDENCE: NT-ing sprod alone cut k1 88->73.5us with FETCH UNCHANGED ->
// the win is the NT service path itself (no L2/LLC allocation churn), not
// residency. p_stream (same 243MB, linear NT streams) = ~26us = 9.6TB/s ->
// ~3x headroom vs k1's cached-path 3.3TB/s. THIS ROUND: every k1 read goes
// NT (staging dwordx4s were the last cached reads). Inputs lose LLC
// residency (FETCH will rise to ~240MB) but stream at HBM-class rate.
__global__ __launch_bounds__(256, 2)
void k1_spatial(const float* __restrict__ d,  const float* __restrict__ cd,
                const float* __restrict__ s,  const float* __restrict__ gx,
                const float* __restrict__ cgx, const float* __restrict__ sprod,
                const float* __restrict__ ws, float2* __restrict__ buf) {
    __shared__ float lds[16128];          // [5][9][256] in + [9][256] ga + [9][256] ca
    float* inL = lds;                     // a*2304 + r*256 + w
    float* gaL = lds + 11520;
    float* caL = lds + 13824;

    const int t  = threadIdx.x;
    const int l  = t & 63;
    const int q  = t >> 6;                // wave id = local out-row
    const int z  = blockIdx.x >> 5;       // slice 0..127 (b*32+c)
    const int rt = blockIdx.x & 31;       // row-tile 0..31
    const int c  = z & 31;

    const float wpc = ws[c];
    const float inv_wp1 = frcp(wpc + 1.0f);
    const float inv_sumsw = ws[1344];
    const float* sw_c = ws + 32 + c * 9;

    const int ho0     = rt * 4;
    const int h_top   = 2 * ho0 - 1;
    const bool top    = (rt == 0);
    const int h_start = top ? 0 : h_top;       // first staged global row
    const int nf4     = top ? 512 : 576;       // float4s per array (8 or 9 rows)
    const int dof     = top ? 256 : 0;         // LDS float shift (rows 1..8)
    const int gbase   = z * (Hv * Wv) + h_start * Wv;

    // ---- staging loads: 5 long contiguous NT streams (regs) ----
    f4v st[5][3];
#pragma unroll
    for (int a = 0; a < 5; ++a) {
        const float* gp = (a == 0) ? d : (a == 1) ? cd : (a == 2) ? s
                        : (a == 3) ? gx : cgx;
#pragma unroll
        for (int k = 0; k < 3; ++k) {
            const int o = t + k * 256;         // float4 index within array block
            if (o < nf4)
                st[a][k] = __builtin_nontemporal_load(
                               (const f4v*)(gp + gbase + 4 * o));
        }
    }
    // sprod for this thread's 2 output pixels (NT, once-read)
    const int ho  = ho0 + q;
    const int sp0 = (z * 9 * HOv + ho) * WOv + 2 * l;
    f2v sp[9];
#pragma unroll
    for (int k = 0; k < 9; ++k)
        sp[k] = __builtin_nontemporal_load(
                    (const f2v*)(sprod + sp0 + k * NPIX));

    // ---- LDS fill (ds_write_b128, conflict-free: lanes consecutive) ----
#pragma unroll
    for (int a = 0; a < 5; ++a) {
#pragma unroll
        for (int k = 0; k < 3; ++k) {
            const int o = t + k * 256;
            if (o < nf4)
                *(f4v*)(inL + a * 2304 + dof + 4 * o) = st[a][k];
        }
    }
    __syncthreads();

    // ---- stage A: pointwise, one px per (thread, row): r=j, w=t ----
#pragma unroll
    for (int j = 0; j < 9; ++j) {
        const int o = j * 256 + t;
        const float dV  = inL[0 * 2304 + o];
        const float cdV = inL[1 * 2304 + o];
        const float sV  = inL[2 * 2304 + o];
        const float gV  = inL[3 * 2304 + o];
        const float cV  = inL[4 * 2304 + o];
        const bool mL = (t != Wv - 1);         // pad_r zeros last col
        const bool mR = (t != 0);              // pad_l zeros first col
        const float dL  = mL ? dV  : 0.f;
        const float cdL = mL ? cdV : 0.f;
        const float sL  = mL ? sV  : 0.f;
        const float dR  = mR ? dV  : 0.f;
        const float cdR = mR ? cdV : 0.f;
        const float sR  = mR ? sV  : 0.f;
        const float cgx_ds = sV * sL * sR * cdL * cdR;
        const float height = (cdL * dL + cdR * dR) * frcp(cdL + cdR + EPSF);
        const float gx_ds  = (dR - dL) * 0.5f * frcp(height + EPSF);
        const float a_ = wpc * cV;
        const float g_ = (a_ * gV + cgx_ds * gx_ds) * frcp(a_ + cgx_ds + EPSF);
        const float c_ = (a_ + cgx_ds) * inv_wp1;
        const bool vrow = (j > 0) || !top;     // LDS row 0 invalid only for rt==0
        gaL[o] = vrow ? g_ : 0.f;
        caL[o] = vrow ? c_ : 0.f;
    }
    __syncthreads();

    // ---- 9-tap gather from LDS + sprod + sw ----
    float n0 = 0.f, d0 = 0.f, n1 = 0.f, d1 = 0.f;
#pragma unroll
    for (int ki = 0; ki < 3; ++ki) {
        const int ro = (2 * q + ki) * 256;
        const float4 g4 = *(const float4*)(gaL + ro + 4 * l);
        const float4 c4 = *(const float4*)(caL + ro + 4 * l);
        const int eo = ro + (l ? 4 * l - 1 : 0);
        float geL = gaL[eo];
        float ceL = caL[eo];
        geL = l ? geL : 0.f;                   // col -1 tap is zero
        ceL = l ? ceL : 0.f;
        const float sw0 = sw_c[3 * ki + 0];
        const float sw1 = sw_c[3 * ki + 1];
        const float sw2 = sw_c[3 * ki + 2];
        float cp;
        // pixel wo0 = 2l : taps cols 4l-1, 4l, 4l+1
        cp = ceL  * sp[3 * ki + 0].x * sw0; d0 += cp; n0 = fmaf(cp, geL,  n0);
        cp = c4.x * sp[3 * ki + 1].x * sw1; d0 += cp; n0 = fmaf(cp, g4.x, n0);
        cp = c4.y * sp[3 * ki + 2].x * sw2; d0 += cp; n0 = fmaf(cp, g4.y, n0);
        // pixel wo1 = 2l+1 : taps cols 4l+1, 4l+2, 4l+3
        cp = c4.y * sp[3 * ki + 0].y * sw0; d1 += cp; n1 = fmaf(cp, g4.y, n1);
        cp = c4.z * sp[3 * ki + 1].y * sw1; d1 += cp; n1 = fmaf(cp, g4.z, n1);
        cp = c4.w * sp[3 * ki + 2].y * sw2; d1 += cp; n1 = fmaf(cp, g4.w, n1);
    }
    const float gx0 = n0 * frcp(d0 + EPSF);
    const float cg0 = d0 * inv_sumsw;
    const float gx1 = n1 * frcp(d1 + EPSF);
    const float cg1 = d1 * inv_sumsw;
    float4 ov = {cg0 * gx0, cg0, cg1 * gx1, cg1};
    *(float4*)(buf + (size_t)z * NPIX + ho * WOv + 2 * l) = ov;
}

// ================= K2: 32->32 channel mix (o split in 2 groups) ===========
// out is write-once/never-read: NT stores keep it from occupying LLC.
__global__ __launch_bounds__(256, 2)
void k2_channel(const float2* __restrict__ buf, const float* __restrict__ ws,
                const float* __restrict__ bias, float* __restrict__ out) {
    const int pg  = blockIdx.x * 256 + threadIdx.x;  // 0..65535
    const int b   = pg >> 14;
    const int pp  = pg & (NPIX - 1);
    const int grp = blockIdx.y;                      // 0..1
    const float* cw_t = ws + 320;
    const float inv_sumcw = ws[1345];

    const int cbase = b * Cv * NPIX + pp;

    float2 v[Cv];
#pragma unroll
    for (int cc = 0; cc < Cv; ++cc)
        v[cc] = gload2((const float*)(buf + cbase + cc * NPIX));

    vm_drain();

    float nom2[16], den2[16];
#pragma unroll
    for (int i = 0; i < 16; ++i) { nom2[i] = 0.f; den2[i] = 0.f; }

#pragma unroll
    for (int cc = 0; cc < Cv; ++cc) {
#pragma unroll
        for (int oi = 0; oi < 16; ++oi) {
            const float w_ = cw_t[(grp * 16 + oi) * Cv + cc];  // uniform
            nom2[oi] = fmaf(v[cc].x, w_, nom2[oi]);
            den2[oi] = fmaf(v[cc].y, w_, den2[oi]);
        }
    }
#pragma unroll
    for (int oi = 0; oi < 16; ++oi) {
        const int o = grp * 16 + oi;
        const int p = (b * Ov + o) * NPIX + pp;
        const float dn = den2[oi];
        const float g  = nom2[oi] * frcp(dn + EPSF) + bias[o];
        __builtin_nontemporal_store(g * 2.0f, out + p);
        __builtin_nontemporal_store(dn * inv_sumcw * 0.25f, out + HALF_OUT + p);
    }
}

// ================= fallback: fully fused (round-1) kernel =================
#define TH 4
#define TW 32
#define IH 9
#define IW 65
#define IWP 66
#define NTILE (IH * IW)

__global__ __launch_bounds__(128)
void main_kernel(const float* __restrict__ d,  const float* __restrict__ cd,
                 const float* __restrict__ s,  const float* __restrict__ gx,
                 const float* __restrict__ cgx, const float* __restrict__ sprod,
                 const float* __restrict__ bias, const float* __restrict__ ws,
                 float* __restrict__ out) {
    __shared__ float lgx[IH][IWP];
    __shared__ float lcgx[IH][IWP];
    const int t    = threadIdx.x;
    const int wo_l = t & 31;
    const int ho_l = t >> 5;
    const int wo0  = blockIdx.x * TW;
    const int ho0  = blockIdx.y * TH;
    const int b    = blockIdx.z;
    const int ho   = ho0 + ho_l;
    const int wo   = wo0 + wo_l;
    const float* sw_t = ws + 32;
    const float* cw_t = ws + 320;
    const float inv_sumsw = ws[1344];
    const float inv_sumcw = ws[1345];
    float nom2[Ov], den2[Ov];
#pragma unroll
    for (int o = 0; o < Ov; ++o) { nom2[o] = 0.f; den2[o] = 0.f; }
    const int h_base = 2 * ho0 - 1;
    const int w_base = 2 * wo0 - 1;
    for (int c = 0; c < Cv; ++c) {
        const float wpc = ws[c];
        const float inv_wp1 = frcp(wpc + 1.0f);
        const int ibase = (b * Cv + c) * (Hv * Wv);
        for (int idx = t; idx < NTILE; idx += 128) {
            const int r  = idx / IW;
            const int cc = idx - r * IW;
            const int h  = h_base + r;
            const int w  = w_base + cc;
            float gxn = 0.f, cgxn = 0.f;
            if ((unsigned)h < (unsigned)Hv && (unsigned)w < (unsigned)Wv) {
                const int p = ibase + h * Wv + w;
                const float dv = d[p], cdv = cd[p], sv = s[p];
                const float gxv = gx[p], cgxv = cgx[p];
                const bool mLb = (w != Wv - 1);
                const bool mRb = (w != 0);
                const float dL = mLb ? dv : 0.f, cdL = mLb ? cdv : 0.f, sL = mLb ? sv : 0.f;
                const float dR = mRb ? dv : 0.f, cdR = mRb ? cdv : 0.f, sR = mRb ? sv : 0.f;
                const float cgx_ds = sv * sL * sR * cdL * cdR;
                const float height = (cdL * dL + cdR * dR) * frcp(cdL + cdR + EPSF);
                const float gx_ds  = (dR - dL) * 0.5f * frcp(height + EPSF);
                const float a = wpc * cgxv;
                gxn  = (a * gxv + cgx_ds * gx_ds) * frcp(a + cgx_ds + EPSF);
                cgxn = (a + cgx_ds) * inv_wp1;
            }
            lgx[r][cc]  = gxn;
            lcgx[r][cc] = cgxn;
        }
        __syncthreads();
        const int spb = ((b * Cv + c) * 9 * HOv + ho) * WOv + wo;
        float nom = 0.f, den = 0.f;
#pragma unroll
        for (int k = 0; k < 9; ++k) {
            const int ki = k / 3;
            const int kj = k - ki * 3;
            const float gxr  = lgx[2 * ho_l + ki][2 * wo_l + kj];
            const float cgxr = lcgx[2 * ho_l + ki][2 * wo_l + kj];
            const float spv  = sprod[spb + k * NPIX];
            const float cp   = cgxr * spv * sw_t[c * 9 + k];
            den += cp;
            nom = fmaf(cp, gxr, nom);
        }
        const float gx_sp  = nom * frcp(den + EPSF);
        const float cgx_sp = den * inv_sumsw;
        const float t1 = cgx_sp * gx_sp;
#pragma unroll
        for (int o = 0; o < Ov; ++o) {
            const float w_ = cw_t[o * Cv + c];
            nom2[o] = fmaf(t1, w_, nom2[o]);
            den2[o] = fmaf(cgx_sp, w_, den2[o]);
        }
        __syncthreads();
    }
#pragma unroll
    for (int o = 0; o < Ov; ++o) {
        const int p = ((b * Ov + o) * HOv + ho) * WOv + wo;
        const float dn = den2[o];
        const float g  = nom2[o] * frcp(dn + EPSF) + bias[o];
        out[p]            = g * 2.0f;
        out[HALF_OUT + p] = dn * inv_sumcw * 0.25f;
    }
}

extern "C" void kernel_launch(void* const* d_in, const int* in_sizes, int n_in,
                              void* d_out, int out_size, void* d_ws, size_t ws_size,
                              hipStream_t stream) {
    const float* d_ptr    = (const float*)d_in[0];
    const float* cd_ptr   = (const float*)d_in[1];
    const float* s_ptr    = (const float*)d_in[2];
    // d_in[3] = cs : unused by the reference
    const float* gx_ptr   = (const float*)d_in[4];
    const float* cgx_ptr  = (const float*)d_in[5];
    const float* sp_ptr   = (const float*)d_in[6];
    const float* wp_ptr   = (const float*)d_in[7];
    const float* sw_ptr   = (const float*)d_in[8];
    const float* cw_ptr   = (const float*)d_in[9];
    const float* bias_ptr = (const float*)d_in[10];
    float* out = (float*)d_out;
    float* ws  = (float*)d_ws;

    prep_kernel<<<1, 256, 0, stream>>>(wp_ptr, sw_ptr, cw_ptr, ws);

    if (ws_size >= WS_NEEDED) {
        float2* buf = (float2*)(ws + WS_BUF_OFF);
        // 4096 blocks = 128 slices x 32 row-tiles; 4 out rows/block.
        k1_spatial<<<4096, 256, 0, stream>>>(d_ptr, cd_ptr, s_ptr, gx_ptr, cgx_ptr,
                                             sp_ptr, ws, buf);
        dim3 g2((Bv * NPIX) / 256, 2, 1);        // 256 x 2 blocks
        k2_channel<<<g2, 256, 0, stream>>>(buf, ws, bias_ptr, out);
    } else {
        dim3 grid(WOv / TW, HOv / TH, Bv);
        main_kernel<<<grid, 128, 0, stream>>>(d_ptr, cd_ptr, s_ptr, gx_ptr, cgx_ptr,
                                              sp_ptr, bias_ptr, ws, out);
    }
}